// Round 1
// baseline (41.984 us; speedup 1.0000x reference)
//
#include <hip/hip_runtime.h>

#define KSIZE 5
#define HALF 2
#define TILE_H 8
#define IMG_W 512
#define IMG_H 512
#define NPAD (TILE_H + 2 * HALF)   // 12 padded rows per tile
#define NTHREADS 256

__device__ __forceinline__ int reflect_idx(int i, int n) {
    // jnp.pad mode='reflect' (edge not repeated)
    if (i < 0) i = -i;
    if (i >= n) i = 2 * n - 2 - i;
    return i;
}

__global__ __launch_bounds__(NTHREADS)
void usm_kernel(const float* __restrict__ img,
                const float* __restrict__ params,
                float* __restrict__ out) {
    __shared__ float tmp[NPAD][IMG_W];   // horizontally-convolved rows

    const int bc = blockIdx.y;           // b*3 + c
    const int b  = bc / 3;
    const int h0 = blockIdx.x * TILE_H;
    const int tid = threadIdx.x;

    // --- per-batch gaussian taps + sharpen amount (redundant per thread, cheap)
    float sigma  = 2.0f * params[b * 2 + 0];
    sigma        = fmaxf(sigma, 0.001f);
    const float amount = 2.0f * params[b * 2 + 1];

    float k[KSIZE];
    float ksum = 0.0f;
    const float inv2s2 = 1.0f / (2.0f * sigma * sigma);
#pragma unroll
    for (int i = 0; i < KSIZE; ++i) {
        const float x = (float)(i - HALF);
        k[i] = expf(-x * x * inv2s2);
        ksum += k[i];
    }
    const float kinv = 1.0f / ksum;
#pragma unroll
    for (int i = 0; i < KSIZE; ++i) k[i] *= kinv;

    const float* src = img + (size_t)bc * IMG_H * IMG_W;

    // --- phase 1: horizontal conv (reflect on W), NPAD rows into LDS
    for (int r = 0; r < NPAD; ++r) {
        const int gh = reflect_idx(h0 + r - HALF, IMG_H);
        const float* row = src + (size_t)gh * IMG_W;
        for (int w = tid; w < IMG_W; w += NTHREADS) {
            float s = 0.0f;
#pragma unroll
            for (int i = 0; i < KSIZE; ++i) {
                const int gw = reflect_idx(w + i - HALF, IMG_W);
                s += k[i] * row[gw];
            }
            tmp[r][w] = s;
        }
    }
    __syncthreads();

    // --- phase 2: vertical conv + unsharp mask + clip, coalesced stores
    float* dst = out + (size_t)bc * IMG_H * IMG_W;
    for (int r = 0; r < TILE_H; ++r) {
        const float* row  = src + (size_t)(h0 + r) * IMG_W;
        float*       orow = dst + (size_t)(h0 + r) * IMG_W;
        for (int w = tid; w < IMG_W; w += NTHREADS) {
            float blur = 0.0f;
#pragma unroll
            for (int j = 0; j < KSIZE; ++j) blur += k[j] * tmp[r + j][w];
            const float o = row[w];
            float v = o + amount * (o - blur);
            v = fminf(fmaxf(v, 0.0f), 1.0f);
            orow[w] = v;
        }
    }
}

extern "C" void kernel_launch(void* const* d_in, const int* in_sizes, int n_in,
                              void* d_out, int out_size, void* d_ws, size_t ws_size,
                              hipStream_t stream) {
    const float* img    = (const float*)d_in[0];
    const float* params = (const float*)d_in[1];
    float* out = (float*)d_out;

    dim3 grid(IMG_H / TILE_H, 16 * 3);   // (64, 48)
    dim3 block(NTHREADS);
    usm_kernel<<<grid, block, 0, stream>>>(img, params, out);
}

// Round 2
// 28.344 us; speedup vs baseline: 1.4812x; 1.4812x over previous
//
#include <hip/hip_runtime.h>

#define KSIZE 5
#define HALF 2
#define TILE_H 8
#define IMG_W 512
#define IMG_H 512
#define NPAD (TILE_H + 2 * HALF)   // 12 padded rows per tile
#define NTHREADS 256
#define NWAVES (NTHREADS / 64)

__device__ __forceinline__ int reflect_idx(int i, int n) {
    // jnp.pad mode='reflect' (edge not repeated)
    if (i < 0) i = -i;
    if (i >= n) i = 2 * n - 2 - i;
    return i;
}

__global__ __launch_bounds__(NTHREADS)
void usm_kernel(const float* __restrict__ img,
                const float* __restrict__ params,
                float* __restrict__ out) {
    __shared__ __align__(16) float tmp[NPAD][IMG_W];   // horizontally-convolved rows

    const int bc  = blockIdx.y;          // b*3 + c
    const int b   = bc / 3;
    const int h0  = blockIdx.x * TILE_H;
    const int tid = threadIdx.x;

    // --- per-batch gaussian taps + sharpen amount (redundant per thread, cheap)
    float sigma  = 2.0f * params[b * 2 + 0];
    sigma        = fmaxf(sigma, 0.001f);
    const float amount = 2.0f * params[b * 2 + 1];

    float k[KSIZE];
    float ksum = 0.0f;
    const float inv2s2 = 1.0f / (2.0f * sigma * sigma);
#pragma unroll
    for (int i = 0; i < KSIZE; ++i) {
        const float x = (float)(i - HALF);
        k[i] = expf(-x * x * inv2s2);
        ksum += k[i];
    }
    const float kinv = 1.0f / ksum;
#pragma unroll
    for (int i = 0; i < KSIZE; ++i) k[i] *= kinv;

    const float* src = img + (size_t)bc * IMG_H * IMG_W;

    // --- phase 1: horizontal conv, vectorized. One wave owns one row:
    // lane owns 8 px (two float4), halos via shfl within the wave.
    const int wave = tid >> 6;
    const int lane = tid & 63;

    for (int r = wave; r < NPAD; r += NWAVES) {
        const int gh = reflect_idx(h0 + r - HALF, IMG_H);
        const float4* row4 = (const float4*)(src + (size_t)gh * IMG_W);
        const float4 a = row4[2 * lane];
        const float4 b4 = row4[2 * lane + 1];

        // left halo: x[base-2]=prev.b.z, x[base-1]=prev.b.w
        float lm2 = __shfl_up(b4.z, 1);
        float lm1 = __shfl_up(b4.w, 1);
        // right halo: x[base+8]=next.a.x, x[base+9]=next.a.y
        float rp0 = __shfl_down(a.x, 1);
        float rp1 = __shfl_down(a.y, 1);
        if (lane == 0)  { lm2 = a.z;  lm1 = a.y; }   // reflect: x[-2]=x[2], x[-1]=x[1]
        if (lane == 63) { rp0 = b4.z; rp1 = b4.y; }  // reflect: x[512]=x[510], x[513]=x[509]

        float x[12];
        x[0] = lm2; x[1] = lm1;
        x[2] = a.x; x[3] = a.y; x[4] = a.z; x[5] = a.w;
        x[6] = b4.x; x[7] = b4.y; x[8] = b4.z; x[9] = b4.w;
        x[10] = rp0; x[11] = rp1;

        float t[8];
#pragma unroll
        for (int i = 0; i < 8; ++i) {
            float s = 0.0f;
#pragma unroll
            for (int j = 0; j < KSIZE; ++j) s += k[j] * x[i + j];
            t[i] = s;
        }
        float4* dstl = (float4*)&tmp[r][8 * lane];
        dstl[0] = make_float4(t[0], t[1], t[2], t[3]);
        dstl[1] = make_float4(t[4], t[5], t[6], t[7]);
    }
    __syncthreads();

    // --- phase 2: vertical conv + unsharp mask + clip, float4 everywhere
    float* dst = out + (size_t)bc * IMG_H * IMG_W;
    const int w4 = tid & 127;        // float4 column 0..127
    const int rr = tid >> 7;         // 0..1

    for (int r = rr; r < TILE_H; r += 2) {
        float4 blur = make_float4(0.f, 0.f, 0.f, 0.f);
#pragma unroll
        for (int j = 0; j < KSIZE; ++j) {
            const float4 t = *(const float4*)&tmp[r + j][4 * w4];
            blur.x += k[j] * t.x;
            blur.y += k[j] * t.y;
            blur.z += k[j] * t.z;
            blur.w += k[j] * t.w;
        }
        const float4 o = ((const float4*)(src + (size_t)(h0 + r) * IMG_W))[w4];
        float4 v;
        v.x = fminf(fmaxf(o.x + amount * (o.x - blur.x), 0.0f), 1.0f);
        v.y = fminf(fmaxf(o.y + amount * (o.y - blur.y), 0.0f), 1.0f);
        v.z = fminf(fmaxf(o.z + amount * (o.z - blur.z), 0.0f), 1.0f);
        v.w = fminf(fmaxf(o.w + amount * (o.w - blur.w), 0.0f), 1.0f);
        ((float4*)(dst + (size_t)(h0 + r) * IMG_W))[w4] = v;
    }
}

extern "C" void kernel_launch(void* const* d_in, const int* in_sizes, int n_in,
                              void* d_out, int out_size, void* d_ws, size_t ws_size,
                              hipStream_t stream) {
    const float* img    = (const float*)d_in[0];
    const float* params = (const float*)d_in[1];
    float* out = (float*)d_out;

    dim3 grid(IMG_H / TILE_H, 16 * 3);   // (64, 48)
    dim3 block(NTHREADS);
    usm_kernel<<<grid, block, 0, stream>>>(img, params, out);
}

// Round 3
// 25.861 us; speedup vs baseline: 1.6234x; 1.0960x over previous
//
#include <hip/hip_runtime.h>

#define KSIZE 5
#define HALF 2
#define IMG_W 512
#define IMG_H 512
#define CHUNK 8                    // output rows per wave
#define NLOADS (CHUNK + 2 * HALF)  // 12 input rows per wave
#define NTHREADS 256
#define NWAVES (NTHREADS / 64)

__device__ __forceinline__ int reflect_idx(int i, int n) {
    // jnp.pad mode='reflect' (edge not repeated)
    if (i < 0) i = -i;
    if (i >= n) i = 2 * n - 2 - i;
    return i;
}

__global__ __launch_bounds__(NTHREADS)
void usm_kernel(const float* __restrict__ img,
                const float* __restrict__ params,
                float* __restrict__ out) {
    const int bc   = blockIdx.y;         // b*3 + c
    const int b    = bc / 3;
    const int wave = threadIdx.x >> 6;
    const int lane = threadIdx.x & 63;
    const int r0   = (blockIdx.x * NWAVES + wave) * CHUNK;

    // --- per-batch gaussian taps + sharpen amount
    float sigma  = 2.0f * params[b * 2 + 0];
    sigma        = fmaxf(sigma, 0.001f);
    const float amount = 2.0f * params[b * 2 + 1];

    float k[KSIZE];
    float ksum = 0.0f;
    const float inv2s2 = 1.0f / (2.0f * sigma * sigma);
#pragma unroll
    for (int i = 0; i < KSIZE; ++i) {
        const float x = (float)(i - HALF);
        k[i] = expf(-x * x * inv2s2);
        ksum += k[i];
    }
    const float kinv = 1.0f / ksum;
#pragma unroll
    for (int i = 0; i < KSIZE; ++i) k[i] *= kinv;

    const float* src = img + (size_t)bc * IMG_H * IMG_W;
    float*       dst = out + (size_t)bc * IMG_H * IMG_W;

    float h[KSIZE][8];   // ring of horizontally-convolved rows (static-indexed)
    float o[3][8];       // ring of original rows (static-indexed)

#pragma unroll
    for (int s = 0; s < NLOADS; ++s) {
        // ---- load input row (reflect on H), 8 px per lane as two float4
        const int ri = reflect_idx(r0 + s - HALF, IMG_H);
        const float4* row4 = (const float4*)(src + (size_t)ri * IMG_W);
        const float4 a  = row4[2 * lane];
        const float4 b4 = row4[2 * lane + 1];

        // ---- horizontal halos via intra-wave shfl (wave owns the whole row)
        float lm2 = __shfl_up(b4.z, 1);
        float lm1 = __shfl_up(b4.w, 1);
        float rp0 = __shfl_down(a.x, 1);
        float rp1 = __shfl_down(a.y, 1);
        if (lane == 0)  { lm2 = a.z;  lm1 = a.y; }   // reflect: x[-2]=x[2], x[-1]=x[1]
        if (lane == 63) { rp0 = b4.z; rp1 = b4.y; }  // reflect: x[512]=x[510], x[513]=x[509]

        float x[12];
        x[0] = lm2;  x[1] = lm1;
        x[2] = a.x;  x[3] = a.y;  x[4] = a.z;  x[5] = a.w;
        x[6] = b4.x; x[7] = b4.y; x[8] = b4.z; x[9] = b4.w;
        x[10] = rp0; x[11] = rp1;

        // ---- horizontal conv -> ring slot s%5
#pragma unroll
        for (int i = 0; i < 8; ++i) {
            float s0 = 0.0f;
#pragma unroll
            for (int j = 0; j < KSIZE; ++j) s0 += k[j] * x[i + j];
            h[s % KSIZE][i] = s0;
        }

        // ---- keep original row in ring slot s%3 (needed when it's the center)
        o[s % 3][0] = a.x;  o[s % 3][1] = a.y;  o[s % 3][2] = a.z;  o[s % 3][3] = a.w;
        o[s % 3][4] = b4.x; o[s % 3][5] = b4.y; o[s % 3][6] = b4.z; o[s % 3][7] = b4.w;

        // ---- once 5 h-rows are live, emit output row ro = r0 + s - 4
        if (s >= 2 * HALF) {
            const int ro = r0 + s - 2 * HALF;
            const int oc = (s - HALF) % 3;   // orig ring slot holding row ro
            float v[8];
#pragma unroll
            for (int i = 0; i < 8; ++i) {
                float blur = 0.0f;
#pragma unroll
                for (int j = 0; j < KSIZE; ++j) blur += k[j] * h[(s - 2 * HALF + j) % KSIZE][i];
                const float orig = o[oc][i];
                float vv = orig + amount * (orig - blur);
                v[i] = fminf(fmaxf(vv, 0.0f), 1.0f);
            }
            float4* dro = (float4*)(dst + (size_t)ro * IMG_W);
            dro[2 * lane]     = make_float4(v[0], v[1], v[2], v[3]);
            dro[2 * lane + 1] = make_float4(v[4], v[5], v[6], v[7]);
        }
    }
}

extern "C" void kernel_launch(void* const* d_in, const int* in_sizes, int n_in,
                              void* d_out, int out_size, void* d_ws, size_t ws_size,
                              hipStream_t stream) {
    const float* img    = (const float*)d_in[0];
    const float* params = (const float*)d_in[1];
    float* out = (float*)d_out;

    dim3 grid(IMG_H / (CHUNK * NWAVES), 16 * 3);   // (16, 48)
    dim3 block(NTHREADS);
    usm_kernel<<<grid, block, 0, stream>>>(img, params, out);
}

// Round 4
// 24.719 us; speedup vs baseline: 1.6984x; 1.0462x over previous
//
#include <hip/hip_runtime.h>

#define KSIZE 5
#define HALF 2
#define IMG_W 512
#define IMG_H 512
#define HALF_W 256                 // px per wave (half a row)
#define CHUNK 8                    // output rows per wave
#define NLOADS (CHUNK + 2 * HALF)  // 12 input rows per wave
#define NTHREADS 256
#define NWAVES (NTHREADS / 64)

__device__ __forceinline__ int reflect_idx(int i, int n) {
    // jnp.pad mode='reflect' (edge not repeated)
    if (i < 0) i = -i;
    if (i >= n) i = 2 * n - 2 - i;
    return i;
}

__global__ __launch_bounds__(NTHREADS)
void usm_kernel(const float* __restrict__ img,
                const float* __restrict__ params,
                float* __restrict__ out) {
    const int bc     = blockIdx.y;          // b*3 + c
    const int b      = bc / 3;
    const int half   = blockIdx.x & 1;      // which half-row (0: px 0..255, 1: px 256..511)
    const int rowgrp = blockIdx.x >> 1;
    const int wave   = threadIdx.x >> 6;
    const int lane   = threadIdx.x & 63;
    const int r0     = (rowgrp * NWAVES + wave) * CHUNK;
    const int c0     = half * HALF_W;       // column base of this wave

    // --- per-batch gaussian taps + sharpen amount
    float sigma  = 2.0f * params[b * 2 + 0];
    sigma        = fmaxf(sigma, 0.001f);
    const float amount = 2.0f * params[b * 2 + 1];

    float k[KSIZE];
    float ksum = 0.0f;
    const float inv2s2 = 1.0f / (2.0f * sigma * sigma);
#pragma unroll
    for (int i = 0; i < KSIZE; ++i) {
        const float x = (float)(i - HALF);
        k[i] = expf(-x * x * inv2s2);
        ksum += k[i];
    }
    const float kinv = 1.0f / ksum;
#pragma unroll
    for (int i = 0; i < KSIZE; ++i) k[i] *= kinv;

    const float* src = img + (size_t)bc * IMG_H * IMG_W;
    float*       dst = out + (size_t)bc * IMG_H * IMG_W;

    float h[KSIZE][4];   // ring of horizontally-convolved rows (static-indexed)
    float o[3][4];       // ring of original rows (static-indexed)

#pragma unroll
    for (int s = 0; s < NLOADS; ++s) {
        // ---- load input row slice (reflect on H): one float4 per lane, contiguous 1KB/wave
        const int ri = reflect_idx(r0 + s - HALF, IMG_H);
        const float* row = src + (size_t)ri * IMG_W;
        const float4 a = *(const float4*)(row + c0 + 4 * lane);

        // ---- horizontal halos via intra-wave shfl
        float lm2 = __shfl_up(a.z, 1);    // px 4l-2
        float lm1 = __shfl_up(a.w, 1);    // px 4l-1
        float rp0 = __shfl_down(a.x, 1);  // px 4l+4
        float rp1 = __shfl_down(a.y, 1);  // px 4l+5
        if (lane == 0) {
            if (half == 0) { lm2 = a.z; lm1 = a.y; }          // reflect: x[-2]=x[2], x[-1]=x[1]
            else {
                const float2 e = *(const float2*)(row + HALF_W - 2);  // px 254,255 (L2-hit)
                lm2 = e.x; lm1 = e.y;
            }
        }
        if (lane == 63) {
            if (half == 0) {
                const float2 e = *(const float2*)(row + HALF_W);      // px 256,257 (L2-hit)
                rp0 = e.x; rp1 = e.y;
            } else { rp0 = a.z; rp1 = a.y; }                  // reflect: x[512]=x[510], x[513]=x[509]
        }

        float x[8];
        x[0] = lm2; x[1] = lm1;
        x[2] = a.x; x[3] = a.y; x[4] = a.z; x[5] = a.w;
        x[6] = rp0; x[7] = rp1;

        // ---- horizontal conv -> ring slot s%5
#pragma unroll
        for (int i = 0; i < 4; ++i) {
            float s0 = 0.0f;
#pragma unroll
            for (int j = 0; j < KSIZE; ++j) s0 += k[j] * x[i + j];
            h[s % KSIZE][i] = s0;
        }

        // ---- keep original row in ring slot s%3
        o[s % 3][0] = a.x; o[s % 3][1] = a.y; o[s % 3][2] = a.z; o[s % 3][3] = a.w;

        // ---- once 5 h-rows are live, emit output row ro = r0 + s - 4
        if (s >= 2 * HALF) {
            const int ro = r0 + s - 2 * HALF;
            const int oc = (s - HALF) % 3;   // orig ring slot holding row ro
            float v[4];
#pragma unroll
            for (int i = 0; i < 4; ++i) {
                float blur = 0.0f;
#pragma unroll
                for (int j = 0; j < KSIZE; ++j) blur += k[j] * h[(s - 2 * HALF + j) % KSIZE][i];
                const float orig = o[oc][i];
                float vv = orig + amount * (orig - blur);
                v[i] = fminf(fmaxf(vv, 0.0f), 1.0f);
            }
            *(float4*)(dst + (size_t)ro * IMG_W + c0 + 4 * lane) =
                make_float4(v[0], v[1], v[2], v[3]);
        }
    }
}

extern "C" void kernel_launch(void* const* d_in, const int* in_sizes, int n_in,
                              void* d_out, int out_size, void* d_ws, size_t ws_size,
                              hipStream_t stream) {
    const float* img    = (const float*)d_in[0];
    const float* params = (const float*)d_in[1];
    float* out = (float*)d_out;

    // grid.x: 16 row-groups (4 waves x CHUNK=8 rows each) x 2 half-rows
    dim3 grid((IMG_H / (CHUNK * NWAVES)) * 2, 16 * 3);   // (32, 48)
    dim3 block(NTHREADS);
    usm_kernel<<<grid, block, 0, stream>>>(img, params, out);
}